// Round 1
// baseline (300.714 us; speedup 1.0000x reference)
//
#include <hip/hip_runtime.h>
#include <hip/hip_bf16.h>
#include <stdint.h>

#define B_SZ 8192
#define D_SZ 1024
#define O_SZ 1024
#define E_SZ 8

typedef __bf16 bf16_t;
typedef __bf16 bf16x8 __attribute__((ext_vector_type(8)));
typedef __bf16 bf16x4 __attribute__((ext_vector_type(4)));
typedef float  f32x4  __attribute__((ext_vector_type(4)));

// ---------------- gating: softmax(x @ Wg + bg) over E=8 ----------------
__global__ __launch_bounds__(256) void gating_kernel(
    const float* __restrict__ x, const float* __restrict__ Wg,
    const float* __restrict__ bg, float* __restrict__ gates) {
  const int w = threadIdx.x >> 6, lane = threadIdx.x & 63;
  const int b = blockIdx.x * 4 + w;
  const float* xr = x + (size_t)b * D_SZ;
  float acc[8];
#pragma unroll
  for (int e = 0; e < 8; ++e) acc[e] = 0.f;
  for (int it = 0; it < 16; ++it) {
    int d = it * 64 + lane;
    float xv = xr[d];
    const float4* wr = (const float4*)(Wg + d * 8);
    float4 w0 = wr[0], w1 = wr[1];
    acc[0] += xv * w0.x; acc[1] += xv * w0.y;
    acc[2] += xv * w0.z; acc[3] += xv * w0.w;
    acc[4] += xv * w1.x; acc[5] += xv * w1.y;
    acc[6] += xv * w1.z; acc[7] += xv * w1.w;
  }
#pragma unroll
  for (int off = 32; off >= 1; off >>= 1) {
#pragma unroll
    for (int e = 0; e < 8; ++e) acc[e] += __shfl_xor(acc[e], off, 64);
  }
  if (lane == 0) {
#pragma unroll
    for (int e = 0; e < 8; ++e) acc[e] += bg[e];
    float m = acc[0];
#pragma unroll
    for (int e = 1; e < 8; ++e) m = fmaxf(m, acc[e]);
    float s = 0.f, ex[8];
#pragma unroll
    for (int e = 0; e < 8; ++e) { ex[e] = __expf(acc[e] - m); s += ex[e]; }
    float inv = 1.0f / s;
    float* gr = gates + (size_t)b * 8;
#pragma unroll
    for (int e = 0; e < 8; ++e) gr[e] = ex[e] * inv;
  }
}

// ---------------- x fp32 -> bf16 ----------------
__global__ __launch_bounds__(256) void cvt_x_kernel(
    const float* __restrict__ x, bf16_t* __restrict__ xb) {
  size_t i = (size_t)blockIdx.x * 256 + threadIdx.x;
  float4 v = ((const float4*)x)[i];
  bf16x4 o;
  o[0] = (bf16_t)v.x; o[1] = (bf16_t)v.y; o[2] = (bf16_t)v.z; o[3] = (bf16_t)v.w;
  ((bf16x4*)xb)[i] = o;
}

// ---------------- We [E,D,O] fp32 -> WeT [E,O,D] bf16 ----------------
__global__ __launch_bounds__(256) void transpose_we(
    const float* __restrict__ We, bf16_t* __restrict__ WeT) {
  __shared__ float tile[64][65];
  const int e = blockIdx.z;
  const int d0 = blockIdx.y * 64, o0 = blockIdx.x * 64;
  const int tx = threadIdx.x & 63, ty = threadIdx.x >> 6;
  const float* src = We + (size_t)e * D_SZ * O_SZ;
#pragma unroll
  for (int i = 0; i < 16; ++i) {
    int d = ty + i * 4;
    tile[d][tx] = src[(size_t)(d0 + d) * O_SZ + o0 + tx];
  }
  __syncthreads();
  bf16_t* dst = WeT + (size_t)e * O_SZ * D_SZ;
#pragma unroll
  for (int i = 0; i < 16; ++i) {
    int o = ty + i * 4;
    dst[(size_t)(o0 + o) * D_SZ + d0 + tx] = (bf16_t)tile[tx][o];
  }
}

// ---------------- fused expert GEMM + gate combine ----------------
__device__ __forceinline__ void gload_lds16(const bf16_t* g, char* l) {
  __builtin_amdgcn_global_load_lds(
      (const __attribute__((address_space(1))) void*)g,
      (__attribute__((address_space(3))) void*)l, 16, 0, 0);
}

__global__ __launch_bounds__(256, 2) void moe_gemm(
    const bf16_t* __restrict__ xb,    // [B, D] bf16
    const bf16_t* __restrict__ wet,   // [E, O, D] bf16
    const float* __restrict__ gates,  // [B, E]
    const float* __restrict__ be,     // [E, O]
    float* __restrict__ out)          // [B, O]
{
  __shared__ bf16_t lA[128 * 32];  // 8 KB, XOR-swizzled 16B granules
  __shared__ bf16_t lB[128 * 32];  // 8 KB, rows = o, cols = k
  __shared__ float  lG[128 * 8];   // 4 KB gates for this row-tile

  const int tid = threadIdx.x;
  const int b0 = blockIdx.y * 128;
  const int o0 = blockIdx.x * 128;

  {  // stage gates (barrier provided by first K-step barrier)
    const float* gsrc = gates + (size_t)b0 * 8;
#pragma unroll
    for (int i = 0; i < 4; ++i) lG[tid + 256 * i] = gsrc[tid + 256 * i];
  }

  const int w = tid >> 6;
  const int lane = tid & 63;
  const int wm = (w >> 1) * 64;
  const int wn = (w & 1) * 64;
  const int m16 = lane & 15;
  const int q = lane >> 4;

  // staging: granule gi covers row gi>>2, physical 16B slot gi&3;
  // logical slot = phys ^ ((row>>1)&3)  (bank-conflict swizzle)
  const int gi0 = tid, gi1 = tid + 256;
  const int ar0 = gi0 >> 2, ac0 = (((gi0 & 3) ^ ((gi0 >> 3) & 3)) * 8);
  const int ar1 = gi1 >> 2, ac1 = (((gi1 & 3) ^ ((gi1 >> 3) & 3)) * 8);
  char* lA0 = (char*)lA + w * 64 * 16;
  char* lA1 = (char*)lA + (256 + w * 64) * 16;
  char* lB0 = (char*)lB + w * 64 * 16;
  char* lB1 = (char*)lB + (256 + w * 64) * 16;

  const bf16_t* Abase = xb + (size_t)b0 * D_SZ;

  f32x4 outAcc[4][4];
#pragma unroll
  for (int i = 0; i < 4; ++i)
#pragma unroll
    for (int j = 0; j < 4; ++j) outAcc[i][j] = f32x4{0.f, 0.f, 0.f, 0.f};

  for (int e = 0; e < E_SZ; ++e) {
    const bf16_t* Bbase = wet + ((size_t)e * O_SZ + o0) * D_SZ;
    f32x4 acc[4][4];
#pragma unroll
    for (int i = 0; i < 4; ++i)
#pragma unroll
      for (int j = 0; j < 4; ++j) acc[i][j] = f32x4{0.f, 0.f, 0.f, 0.f};

    for (int kt = 0; kt < D_SZ / 32; ++kt) {
      const int kc = kt * 32;
      __syncthreads();  // previous iter's ds_reads done before overwrite
      gload_lds16(Abase + (size_t)ar0 * D_SZ + kc + ac0, lA0);
      gload_lds16(Abase + (size_t)ar1 * D_SZ + kc + ac1, lA1);
      gload_lds16(Bbase + (size_t)ar0 * D_SZ + kc + ac0, lB0);
      gload_lds16(Bbase + (size_t)ar1 * D_SZ + kc + ac1, lB1);
      __syncthreads();  // compiler drains vmcnt(0) before this barrier

      bf16x8 af[4], bf[4];
#pragma unroll
      for (int i = 0; i < 4; ++i) {
        int r = wm + i * 16 + m16;
        int pg = (q ^ ((r >> 1) & 3)) * 8;
        af[i] = *(const bf16x8*)&lA[r * 32 + pg];
      }
#pragma unroll
      for (int j = 0; j < 4; ++j) {
        int r = wn + j * 16 + m16;
        int pg = (q ^ ((r >> 1) & 3)) * 8;
        bf[j] = *(const bf16x8*)&lB[r * 32 + pg];
      }
#pragma unroll
      for (int i = 0; i < 4; ++i)
#pragma unroll
        for (int j = 0; j < 4; ++j)
          acc[i][j] = __builtin_amdgcn_mfma_f32_16x16x32_bf16(
              af[i], bf[j], acc[i][j], 0, 0, 0);
    }

    // outAcc += g[row,e] * (acc + be[e,col]); C layout: col=lane&15, row=q*4+reg
#pragma unroll
    for (int j = 0; j < 4; ++j) {
      float bec = be[e * O_SZ + o0 + wn + j * 16 + m16];
#pragma unroll
      for (int i = 0; i < 4; ++i) {
#pragma unroll
        for (int rg = 0; rg < 4; ++rg) {
          float gv = lG[(wm + i * 16 + q * 4 + rg) * 8 + e];
          outAcc[i][j][rg] += gv * (acc[i][j][rg] + bec);
        }
      }
    }
  }

#pragma unroll
  for (int i = 0; i < 4; ++i)
#pragma unroll
    for (int rg = 0; rg < 4; ++rg) {
      float* orow = out + (size_t)(b0 + wm + i * 16 + q * 4 + rg) * O_SZ
                    + o0 + wn + m16;
#pragma unroll
      for (int j = 0; j < 4; ++j) orow[j * 16] = outAcc[i][j][rg];
    }
}

extern "C" void kernel_launch(void* const* d_in, const int* in_sizes, int n_in,
                              void* d_out, int out_size, void* d_ws, size_t ws_size,
                              hipStream_t stream) {
  const float* x  = (const float*)d_in[0];
  const float* Wg = (const float*)d_in[1];
  const float* bg = (const float*)d_in[2];
  const float* We = (const float*)d_in[3];
  const float* be = (const float*)d_in[4];
  float* out = (float*)d_out;

  char* ws = (char*)d_ws;
  float*  gates = (float*)ws;                             // 256 KB
  bf16_t* xb    = (bf16_t*)(ws + (1 << 18));              // 16 MB
  bf16_t* wet   = (bf16_t*)(ws + (1 << 18) + (1 << 24));  // 16 MB
  // total ws use: ~32.25 MB

  gating_kernel<<<B_SZ / 4, 256, 0, stream>>>(x, Wg, bg, gates);
  cvt_x_kernel<<<(B_SZ * D_SZ) / (4 * 256), 256, 0, stream>>>(x, xb);
  transpose_we<<<dim3(O_SZ / 64, D_SZ / 64, E_SZ), 256, 0, stream>>>(We, wet);
  moe_gemm<<<dim3(O_SZ / 128, B_SZ / 128), 256, 0, stream>>>(xb, wet, gates, be, out);
}